// Round 22
// baseline (1031.554 us; speedup 1.0000x reference)
//
#include <hip/hip_runtime.h>

// SNN layer: B=8, S=1024, I=512, H=1024, O=512, T=8
// np reference numerics IDENTIFIED (R21 mask-probe: candidate c3 uniquely
// matches ref at the decisive knife-edge; all-agree outputs always match):
//   BLIS/AOCL-style sgemm, kc = 512:
//     K=512  -> single chunk [512]  : c = ch0         (one sequential chain)
//     K=1024 -> chunks [512,512]    : c = ch0 + ch1   (boundary at k=512)
//   Within chunk: single sequential ascending-k FUSED fma chain.
//   LIF: mem += c; spike = mem>0.5; fired -> 0.0 exactly.
//   Layer2: mm = (mem_prev + delta) + b2, left-assoc.
static constexpr int B_ = 8, S_ = 1024, I_ = 512, H_ = 1024, O_ = 512, T_ = 8;
static constexpr int M_ = B_ * S_;
static constexpr float TH = 0.5f;

// ---------------------------------------------------------------------------
// K1: inp_cur = dot(x, w1^T) + b1 (full-K single chain) -> 8-step LIF ->
// bit-packed spikes. 64x64 tile, 256 threads, 4x4/thread, BK=16.
// ---------------------------------------------------------------------------
__global__ __launch_bounds__(256) void k1(const float* __restrict__ X,
                                          const float* __restrict__ W1,
                                          const float* __restrict__ B1,
                                          unsigned char* __restrict__ SPB) {
  __shared__ float As[16][68];
  __shared__ float Bs[16][68];
  const int tid = threadIdx.x;
  const int tx = tid & 15, ty = tid >> 4;
  const int rowBase = blockIdx.x * 64, colBase = blockIdx.y * 64;
  const int r = tid & 63, p = tid >> 6;

  float acc[4][4];
#pragma unroll
  for (int i = 0; i < 4; ++i)
#pragma unroll
    for (int j = 0; j < 4; ++j) acc[i][j] = 0.f;

  for (int it = 0; it < 32; ++it) {
    {
      float4 va = *(const float4*)&X[(size_t)(rowBase + r) * I_ + it * 16 + p * 4];
      As[p * 4 + 0][r] = va.x; As[p * 4 + 1][r] = va.y;
      As[p * 4 + 2][r] = va.z; As[p * 4 + 3][r] = va.w;
      float4 vb = *(const float4*)&W1[(size_t)(colBase + r) * I_ + it * 16 + p * 4];
      Bs[p * 4 + 0][r] = vb.x; Bs[p * 4 + 1][r] = vb.y;
      Bs[p * 4 + 2][r] = vb.z; Bs[p * 4 + 3][r] = vb.w;
    }
    __syncthreads();
#pragma unroll
    for (int k = 0; k < 16; ++k) {
      float4 rav = *(const float4*)&As[k][ty * 4];
      float4 rbv = *(const float4*)&Bs[k][tx * 4];
      float ra[4] = {rav.x, rav.y, rav.z, rav.w};
      float rb[4] = {rbv.x, rbv.y, rbv.z, rbv.w};
#pragma unroll
      for (int i = 0; i < 4; ++i)
#pragma unroll
        for (int j = 0; j < 4; ++j) acc[i][j] = fmaf(ra[i], rb[j], acc[i][j]);
    }
    __syncthreads();
  }

#pragma unroll
  for (int i = 0; i < 4; ++i) {
    int row = rowBase + ty * 4 + i;
    unsigned char by[4];
#pragma unroll
    for (int j = 0; j < 4; ++j) {
      int col = colBase + tx * 4 + j;
      float c = acc[i][j] + B1[col];  // single chain + b1
      float m = 0.f;
      unsigned bits = 0;
#pragma unroll
      for (int t = 0; t < 8; ++t) {
        m = m + c;
        bool s = m > TH;
        bits |= (s ? 1u : 0u) << t;
        m = s ? 0.f : m;  // reference mem*(mem<=TH): fired -> +0.0
      }
      by[j] = (unsigned char)bits;
    }
    uchar4 pk; pk.x = by[0]; pk.y = by[1]; pk.z = by[2]; pk.w = by[3];
    *(uchar4*)&SPB[(size_t)row * H_ + colBase + tx * 4] = pk;
  }
}

// ---------------------------------------------------------------------------
// K2 (per step t): delta = dot(spike_t, w2^T), chunks [512,512] (boundary at
// tile 32), sequential chain within chunk, delta = ch0 + ch1;
// mm = (mem_prev + delta) + b2; spikes -> out slice t; next mem stashed in
// out slice t+1 (overwritten at t+1).
// ---------------------------------------------------------------------------
__global__ __launch_bounds__(256) void k2(const unsigned char* __restrict__ SP,
                                          const float* __restrict__ W2,
                                          const float* __restrict__ B2,
                                          float* __restrict__ out, int t) {
  __shared__ float As[16][68];
  __shared__ float Bs[16][68];
  const int tid = threadIdx.x;
  const int tx = tid & 15, ty = tid >> 4;
  const int rowBase = blockIdx.x * 64, colBase = blockIdx.y * 64;
  const int r = tid & 63, p = tid >> 6;

  float tot[4][4], cur[4][4];
#pragma unroll
  for (int i = 0; i < 4; ++i)
#pragma unroll
    for (int j = 0; j < 4; ++j) { tot[i][j] = 0.f; cur[i][j] = 0.f; }

  for (int it = 0; it < 64; ++it) {
    if (it == 32) {  // chunk boundary k=512: join, restart chain
#pragma unroll
      for (int i = 0; i < 4; ++i)
#pragma unroll
        for (int j = 0; j < 4; ++j) { tot[i][j] += cur[i][j]; cur[i][j] = 0.f; }
    }
    {
      unsigned u = *(const unsigned*)&SP[(size_t)(rowBase + r) * H_ + it * 16 + p * 4];
      As[p * 4 + 0][r] = (float)((u >> t) & 1u);
      As[p * 4 + 1][r] = (float)((u >> (8 + t)) & 1u);
      As[p * 4 + 2][r] = (float)((u >> (16 + t)) & 1u);
      As[p * 4 + 3][r] = (float)((u >> (24 + t)) & 1u);
      float4 vb = *(const float4*)&W2[(size_t)(colBase + r) * H_ + it * 16 + p * 4];
      Bs[p * 4 + 0][r] = vb.x; Bs[p * 4 + 1][r] = vb.y;
      Bs[p * 4 + 2][r] = vb.z; Bs[p * 4 + 3][r] = vb.w;
    }
    __syncthreads();
#pragma unroll
    for (int k = 0; k < 16; ++k) {
      float4 rav = *(const float4*)&As[k][ty * 4];
      float4 rbv = *(const float4*)&Bs[k][tx * 4];
      float ra[4] = {rav.x, rav.y, rav.z, rav.w};
      float rb[4] = {rbv.x, rbv.y, rbv.z, rbv.w};
#pragma unroll
      for (int i = 0; i < 4; ++i)
#pragma unroll
        for (int j = 0; j < 4; ++j) cur[i][j] = fmaf(ra[i], rb[j], cur[i][j]);
    }
    __syncthreads();
  }

  const int col0 = colBase + tx * 4;
  float4 b2v = *(const float4*)&B2[col0];
#pragma unroll
  for (int i = 0; i < 4; ++i) {
    int row = rowBase + ty * 4 + i;
    int bb = row >> 10;          // row / S_
    int ss = row & (S_ - 1);
    size_t slot_t = (((size_t)bb * T_ + t) * S_ + ss) * O_ + col0;
    float4 mp;
    if (t == 0) mp = make_float4(0.f, 0.f, 0.f, 0.f);
    else mp = *(const float4*)&out[slot_t];  // state stashed by step t-1
    float d[4], mm[4];
#pragma unroll
    for (int j = 0; j < 4; ++j)
      d[j] = tot[i][j] + cur[i][j];          // ch0 + ch1
    mm[0] = (mp.x + d[0]) + b2v.x;           // (mem2 + delta) + b2
    mm[1] = (mp.y + d[1]) + b2v.y;
    mm[2] = (mp.z + d[2]) + b2v.z;
    mm[3] = (mp.w + d[3]) + b2v.w;
    float4 sp, mn;
    sp.x = (mm[0] > TH) ? 1.f : 0.f;  mn.x = (mm[0] > TH) ? 0.f : mm[0];
    sp.y = (mm[1] > TH) ? 1.f : 0.f;  mn.y = (mm[1] > TH) ? 0.f : mm[1];
    sp.z = (mm[2] > TH) ? 1.f : 0.f;  mn.z = (mm[2] > TH) ? 0.f : mm[2];
    sp.w = (mm[3] > TH) ? 1.f : 0.f;  mn.w = (mm[3] > TH) ? 0.f : mm[3];
    *(float4*)&out[slot_t] = sp;      // final spikes for step t
    if (t < T_ - 1) {
      size_t slot_n = (((size_t)bb * T_ + (t + 1)) * S_ + ss) * O_ + col0;
      *(float4*)&out[slot_n] = mn;    // stash state; overwritten at t+1
    }
  }
}

extern "C" void kernel_launch(void* const* d_in, const int* in_sizes, int n_in,
                              void* d_out, int out_size, void* d_ws, size_t ws_size,
                              hipStream_t stream) {
  const float* x  = (const float*)d_in[0];   // (B,S,I)
  const float* w1 = (const float*)d_in[1];   // (H,I)
  const float* b1 = (const float*)d_in[2];   // (H)
  const float* w2 = (const float*)d_in[3];   // (O,H)
  const float* b2 = (const float*)d_in[4];   // (O)
  float* out = (float*)d_out;                // (B,T,S,O) f32

  unsigned char* spikeB = (unsigned char*)d_ws;  // M*H bytes = 8.4 MB

  k1<<<dim3(M_ / 64, H_ / 64), 256, 0, stream>>>(x, w1, b1, spikeB);
  for (int t = 0; t < T_; ++t)
    k2<<<dim3(M_ / 64, O_ / 64), 256, 0, stream>>>(spikeB, w2, b2, out, t);
}